// Round 1
// baseline (342.346 us; speedup 1.0000x reference)
//
#include <hip/hip_runtime.h>
#include <cstdint>

// AdaptiveNet: x[16384,1024] -> fc1(4096)+sigmoid -> grouped(512 groups of 8)+sigmoid -> fc3(256)
// Strategy: bf16 MFMA (16x16x32) for GEMM1 (dominant, 137 GFLOP) with layer-2 fused
// into the epilogue (group = 8 consecutive columns -> 8-lane shfl_xor reduce),
// then bf16 MFMA GEMM3. fp32->bf16 conversion kernels feed the GEMMs.

#define B_ROWS 16384
#define DIN 1024
#define H1  4096
#define H2  512
#define DOUT 256
#define TILE 128
#define BK 32

typedef __bf16 bf16x8 __attribute__((ext_vector_type(8)));
typedef float f32x4 __attribute__((ext_vector_type(4)));

__device__ __forceinline__ unsigned short f2bf(float f) {
    union { float f; uint32_t u; } v; v.f = f;
    uint32_t u = v.u;
    u += 0x7FFFu + ((u >> 16) & 1u);   // round-to-nearest-even
    return (unsigned short)(u >> 16);
}

__device__ __forceinline__ float sigmoidf_fast(float x) {
    return 1.0f / (1.0f + __expf(-x));
}

// fp32 -> bf16, 4 elements/thread
__global__ __launch_bounds__(256) void cvt_kernel(const float* __restrict__ src,
                                                  unsigned short* __restrict__ dst,
                                                  int n4) {
    int i = blockIdx.x * 256 + threadIdx.x;
    if (i >= n4) return;
    float4 v = ((const float4*)src)[i];
    ushort4 o;
    o.x = f2bf(v.x); o.y = f2bf(v.y); o.z = f2bf(v.z); o.w = f2bf(v.w);
    ((ushort4*)dst)[i] = o;
}

__device__ __forceinline__ void load_lds16(const void* g, void* l) {
    __builtin_amdgcn_global_load_lds(
        (const __attribute__((address_space(1))) void*)g,
        (__attribute__((address_space(3))) void*)l, 16, 0, 0);
}

// Core K-loop: C[128,128] tile, A row-major [M,K], B stored as [N,K] (i.e. B^T),
// both bf16. 4 waves, each wave owns a 64x64 quadrant as 4x4 MFMA 16x16 tiles.
template <int K>
__device__ __forceinline__ void gemm_core(const unsigned short* __restrict__ A,
                                          const unsigned short* __restrict__ Bm,
                                          unsigned short* lsA, unsigned short* lsB,
                                          long a_row0, long b_row0,
                                          int lane, int wave, int wm, int wn,
                                          f32x4 acc[4][4]) {
    const int q = lane >> 4, m16 = lane & 15;
    for (int kt = 0; kt < K / BK; ++kt) {
        __syncthreads();                      // protect LDS from prior iter readers
        const int k0 = kt * BK;
#pragma unroll
        for (int i = 0; i < 2; ++i) {
            const int ch = wave * 2 + i;      // chunk: 1024B = 512 elems = 16 rows
            const int e = ch * 512 + lane * 8;
            const int r = e >> 5, c = e & 31;
            load_lds16(A + (a_row0 + r) * K + k0 + c, lsA + ch * 512);
            load_lds16(Bm + (b_row0 + r) * K + k0 + c, lsB + ch * 512);
        }
        __syncthreads();                      // staged (syncthreads drains vmcnt)
        bf16x8 af[4], bfr[4];
#pragma unroll
        for (int r = 0; r < 4; ++r)
            af[r] = *(const bf16x8*)(lsA + (wm + r * 16 + m16) * BK + q * 8);
#pragma unroll
        for (int c = 0; c < 4; ++c)
            bfr[c] = *(const bf16x8*)(lsB + (wn + c * 16 + m16) * BK + q * 8);
#pragma unroll
        for (int r = 0; r < 4; ++r)
#pragma unroll
            for (int c = 0; c < 4; ++c)
                acc[r][c] = __builtin_amdgcn_mfma_f32_16x16x32_bf16(
                    af[r], bfr[c], acc[r][c], 0, 0, 0);
    }
}

// GEMM1: h = sigmoid(x @ W1^T + b1); fused layer2: x2 = sigmoid(groupdot(h,W2)+b2)
// writes x2 as bf16 [16384, 512]
__global__ __launch_bounds__(256, 2) void gemm1_fused(
    const unsigned short* __restrict__ Xb,   // [16384,1024] bf16
    const unsigned short* __restrict__ W1b,  // [4096,1024]  bf16 (N,K)
    const float* __restrict__ b1,            // [4096]
    const float* __restrict__ W2,            // [512*8] flat; W2[g][s] = W2[gn]
    const float* __restrict__ b2,            // [512]
    unsigned short* __restrict__ X2) {       // [16384,512] bf16
    __shared__ __attribute__((aligned(16))) unsigned short lsA[TILE * BK];
    __shared__ __attribute__((aligned(16))) unsigned short lsB[TILE * BK];
    const int tid = threadIdx.x, lane = tid & 63, wave = tid >> 6;
    const int wm = (wave >> 1) * 64, wn = (wave & 1) * 64;
    const long a0 = (long)blockIdx.y * TILE;
    const long n0 = (long)blockIdx.x * TILE;

    f32x4 acc[4][4];
#pragma unroll
    for (int r = 0; r < 4; ++r)
#pragma unroll
        for (int c = 0; c < 4; ++c) acc[r][c] = (f32x4)0.0f;

    gemm_core<DIN>(Xb, W1b, lsA, lsB, a0, n0, lane, wave, wm, wn, acc);

    // Epilogue. C/D layout (m89-verified): col = lane&15, row = (lane>>4)*4 + reg.
    const int q = lane >> 4, m16 = lane & 15;
#pragma unroll
    for (int c = 0; c < 4; ++c) {
        const int gn = (int)n0 + wn + c * 16 + m16;   // h column
        const float w2v = W2[gn];                     // gn == g*8 + s
        const float b1v = b1[gn];
        const int g = gn >> 3;
        const float b2v = b2[g];
#pragma unroll
        for (int r = 0; r < 4; ++r) {
#pragma unroll
            for (int i = 0; i < 4; ++i) {
                const long gm = a0 + wm + r * 16 + q * 4 + i;
                float h = sigmoidf_fast(acc[r][c][i] + b1v);
                float v = h * w2v;
                // group of 8 consecutive columns == 8 adjacent lanes
                v += __shfl_xor(v, 1, 64);
                v += __shfl_xor(v, 2, 64);
                v += __shfl_xor(v, 4, 64);
                if ((lane & 7) == 0)
                    X2[gm * H2 + g] = f2bf(sigmoidf_fast(v + b2v));
            }
        }
    }
}

// GEMM3: out = x2 @ W3^T + b3, fp32 out [16384, 256]
__global__ __launch_bounds__(256, 2) void gemm3_kernel(
    const unsigned short* __restrict__ X2,   // [16384,512] bf16
    const unsigned short* __restrict__ W3b,  // [256,512] bf16 (N,K)
    const float* __restrict__ b3,            // [256]
    float* __restrict__ Out) {               // [16384,256] f32
    __shared__ __attribute__((aligned(16))) unsigned short lsA[TILE * BK];
    __shared__ __attribute__((aligned(16))) unsigned short lsB[TILE * BK];
    const int tid = threadIdx.x, lane = tid & 63, wave = tid >> 6;
    const int wm = (wave >> 1) * 64, wn = (wave & 1) * 64;
    const long a0 = (long)blockIdx.y * TILE;
    const long n0 = (long)blockIdx.x * TILE;

    f32x4 acc[4][4];
#pragma unroll
    for (int r = 0; r < 4; ++r)
#pragma unroll
        for (int c = 0; c < 4; ++c) acc[r][c] = (f32x4)0.0f;

    gemm_core<H2>(X2, W3b, lsA, lsB, a0, n0, lane, wave, wm, wn, acc);

    const int q = lane >> 4, m16 = lane & 15;
#pragma unroll
    for (int c = 0; c < 4; ++c) {
        const int gn = (int)n0 + wn + c * 16 + m16;
        const float b3v = b3[gn];
#pragma unroll
        for (int r = 0; r < 4; ++r) {
#pragma unroll
            for (int i = 0; i < 4; ++i) {
                const long gm = a0 + wm + r * 16 + q * 4 + i;
                Out[gm * DOUT + gn] = acc[r][c][i] + b3v;
            }
        }
    }
}

extern "C" void kernel_launch(void* const* d_in, const int* in_sizes, int n_in,
                              void* d_out, int out_size, void* d_ws, size_t ws_size,
                              hipStream_t stream) {
    const float* x  = (const float*)d_in[0];
    const float* W1 = (const float*)d_in[1];
    const float* b1 = (const float*)d_in[2];
    const float* W2 = (const float*)d_in[3];
    const float* b2 = (const float*)d_in[4];
    const float* W3 = (const float*)d_in[5];
    const float* b3 = (const float*)d_in[6];
    float* out = (float*)d_out;

    char* ws = (char*)d_ws;
    unsigned short* x_bf  = (unsigned short*)ws;                         // 33,554,432 B
    unsigned short* w1_bf = (unsigned short*)(ws + 33554432);            //  8,388,608 B
    unsigned short* w3_bf = (unsigned short*)(ws + 33554432 + 8388608);  //    262,144 B
    unsigned short* x2_bf = (unsigned short*)(ws + 33554432 + 8388608 + 262144); // 16,777,216 B

    {
        int n4 = B_ROWS * DIN / 4;  // 4,194,304
        cvt_kernel<<<(n4 + 255) / 256, 256, 0, stream>>>(x, x_bf, n4);
    }
    {
        int n4 = H1 * DIN / 4;      // 1,048,576
        cvt_kernel<<<(n4 + 255) / 256, 256, 0, stream>>>(W1, w1_bf, n4);
    }
    {
        int n4 = DOUT * H2 / 4;     // 32,768
        cvt_kernel<<<(n4 + 255) / 256, 256, 0, stream>>>(W3, w3_bf, n4);
    }

    // GEMM1 + fused layer 2: grid = (N/128, M/128) = (32, 128)
    gemm1_fused<<<dim3(H1 / TILE, B_ROWS / TILE), 256, 0, stream>>>(
        x_bf, w1_bf, b1, W2, b2, x2_bf);

    // GEMM3: grid = (256/128, 16384/128) = (2, 128)
    gemm3_kernel<<<dim3(DOUT / TILE, B_ROWS / TILE), 256, 0, stream>>>(
        x2_bf, w3_bf, b3, out);
}

// Round 2
// 341.806 us; speedup vs baseline: 1.0016x; 1.0016x over previous
//
#include <hip/hip_runtime.h>
#include <cstdint>

// AdaptiveNet: x[16384,1024] -> fc1(4096)+sigmoid -> grouped(512 groups of 8)+sigmoid -> fc3(256)
// bf16 MFMA (16x16x32). R2: swizzled LDS layout (kills 8-way bank conflicts),
// hoisted staging addresses, merged cvt kernels into one launch.

#define B_ROWS 16384
#define DIN 1024
#define H1  4096
#define H2  512
#define DOUT 256
#define TILE 128
#define BK 32

#define NX4  (B_ROWS * DIN / 4)   // 4194304
#define NW14 (H1 * DIN / 4)       // 1048576
#define NW34 (DOUT * H2 / 4)      // 32768

typedef __bf16 bf16x8 __attribute__((ext_vector_type(8)));
typedef float f32x4 __attribute__((ext_vector_type(4)));

__device__ __forceinline__ unsigned short f2bf(float f) {
    union { float f; uint32_t u; } v; v.f = f;
    uint32_t u = v.u;
    u += 0x7FFFu + ((u >> 16) & 1u);   // round-to-nearest-even
    return (unsigned short)(u >> 16);
}

__device__ __forceinline__ float sigmoidf_fast(float x) {
    return 1.0f / (1.0f + __expf(-x));
}

// one launch converts x, W1, W3 fp32->bf16 (all ranges multiples of 256 threads)
__global__ __launch_bounds__(256) void cvt3_kernel(
    const float* __restrict__ x, const float* __restrict__ w1,
    const float* __restrict__ w3, unsigned short* __restrict__ xo,
    unsigned short* __restrict__ w1o, unsigned short* __restrict__ w3o) {
    int i = blockIdx.x * 256 + threadIdx.x;
    const float* src; unsigned short* dst; int j;
    if (i < NX4)              { src = x;  dst = xo;  j = i; }
    else if (i < NX4 + NW14)  { src = w1; dst = w1o; j = i - NX4; }
    else                      { src = w3; dst = w3o; j = i - NX4 - NW14; }
    float4 v = ((const float4*)src)[j];
    ushort4 o;
    o.x = f2bf(v.x); o.y = f2bf(v.y); o.z = f2bf(v.z); o.w = f2bf(v.w);
    ((ushort4*)dst)[j] = o;
}

__device__ __forceinline__ void load_lds16(const void* g, void* l) {
    __builtin_amdgcn_global_load_lds(
        (const __attribute__((address_space(1))) void*)g,
        (__attribute__((address_space(3))) void*)l, 16, 0, 0);
}

// Core K-loop: C[128,128] tile, A row-major [M,K], B stored as [N,K], both bf16.
// LDS layout swizzle: row r's four 16B k-chunks are rotated by (r>>2)&3, so
// ds_read_b128 of 16 rows at fixed k spreads over all 8 bank-groups (2-way = free).
// Swizzle is realized by permuting each staging lane's global k-chunk; the 4 lanes
// of one row still cover the same 64B global segment (coalescing preserved).
template <int K>
__device__ __forceinline__ void gemm_core(const unsigned short* __restrict__ A,
                                          const unsigned short* __restrict__ Bm,
                                          unsigned short* lsA, unsigned short* lsB,
                                          int a_row0, int b_row0,
                                          int lane, int wave, int wm, int wn,
                                          f32x4 acc[4][4]) {
    const int q = lane >> 4, m16 = lane & 15;

    // ---- staging addresses (loop-invariant) ----
    int gA[2], gB[2], lo[2];
#pragma unroll
    for (int i = 0; i < 2; ++i) {
        const int ch = wave * 2 + i;          // chunk = 16 rows (1 KiB)
        const int r  = ch * 16 + (lane >> 2); // row this lane stages
        const int kc = ((lane & 3) - (lane >> 4)) & 3;  // swizzled k-chunk
        gA[i] = (a_row0 + r) * K + kc * 8;
        gB[i] = (b_row0 + r) * K + kc * 8;
        lo[i] = ch * 512 + lane * 8;
    }
    // ---- fragment-read offsets (loop-invariant) ----
    const int rot = ((q + (m16 >> 2)) & 3) * 8;   // swizzled position within row
    int ra[4], rb[4];
#pragma unroll
    for (int t = 0; t < 4; ++t) {
        ra[t] = (wm + t * 16 + m16) * 32 + rot;
        rb[t] = (wn + t * 16 + m16) * 32 + rot;
    }

    for (int kt = 0; kt < K / BK; ++kt) {
        __syncthreads();                      // protect LDS from prior iter readers
        const int k0 = kt * BK;
#pragma unroll
        for (int i = 0; i < 2; ++i) {
            load_lds16(A + gA[i] + k0, lsA + lo[i]);
            load_lds16(Bm + gB[i] + k0, lsB + lo[i]);
        }
        __syncthreads();                      // staged (syncthreads drains vmcnt)
        bf16x8 af[4], bfr[4];
#pragma unroll
        for (int t = 0; t < 4; ++t) af[t]  = *(const bf16x8*)(lsA + ra[t]);
#pragma unroll
        for (int t = 0; t < 4; ++t) bfr[t] = *(const bf16x8*)(lsB + rb[t]);
#pragma unroll
        for (int r = 0; r < 4; ++r)
#pragma unroll
            for (int c = 0; c < 4; ++c)
                acc[r][c] = __builtin_amdgcn_mfma_f32_16x16x32_bf16(
                    af[r], bfr[c], acc[r][c], 0, 0, 0);
    }
}

// GEMM1: h = sigmoid(x @ W1^T + b1); fused layer2: x2 = sigmoid(groupdot(h,W2)+b2)
__global__ __launch_bounds__(256, 2) void gemm1_fused(
    const unsigned short* __restrict__ Xb,   // [16384,1024] bf16
    const unsigned short* __restrict__ W1b,  // [4096,1024]  bf16 (N,K)
    const float* __restrict__ b1,            // [4096]
    const float* __restrict__ W2,            // [512*8] flat; W2[g][s] = W2[gn]
    const float* __restrict__ b2,            // [512]
    unsigned short* __restrict__ X2) {       // [16384,512] bf16
    __shared__ __attribute__((aligned(16))) unsigned short lsA[TILE * BK];
    __shared__ __attribute__((aligned(16))) unsigned short lsB[TILE * BK];
    const int tid = threadIdx.x, lane = tid & 63, wave = tid >> 6;
    const int wm = (wave >> 1) * 64, wn = (wave & 1) * 64;
    const int a0 = blockIdx.y * TILE;
    const int n0 = blockIdx.x * TILE;

    f32x4 acc[4][4];
#pragma unroll
    for (int r = 0; r < 4; ++r)
#pragma unroll
        for (int c = 0; c < 4; ++c) acc[r][c] = (f32x4)0.0f;

    gemm_core<DIN>(Xb, W1b, lsA, lsB, a0, n0, lane, wave, wm, wn, acc);

    // Epilogue. C/D layout (m89): col = lane&15, row = (lane>>4)*4 + reg.
    const int q = lane >> 4, m16 = lane & 15;
#pragma unroll
    for (int c = 0; c < 4; ++c) {
        const int gn = n0 + wn + c * 16 + m16;        // h column
        const float w2v = W2[gn];                     // gn == g*8 + s
        const float b1v = b1[gn];
        const int g = gn >> 3;
        const float b2v = b2[g];
#pragma unroll
        for (int r = 0; r < 4; ++r) {
#pragma unroll
            for (int i = 0; i < 4; ++i) {
                const int gm = a0 + wm + r * 16 + q * 4 + i;
                float h = sigmoidf_fast(acc[r][c][i] + b1v);
                float v = h * w2v;
                // group of 8 consecutive columns == 8 adjacent lanes
                v += __shfl_xor(v, 1, 64);
                v += __shfl_xor(v, 2, 64);
                v += __shfl_xor(v, 4, 64);
                if ((lane & 7) == 0)
                    X2[gm * H2 + g] = f2bf(sigmoidf_fast(v + b2v));
            }
        }
    }
}

// GEMM3: out = x2 @ W3^T + b3, fp32 out [16384, 256]
__global__ __launch_bounds__(256, 2) void gemm3_kernel(
    const unsigned short* __restrict__ X2,   // [16384,512] bf16
    const unsigned short* __restrict__ W3b,  // [256,512] bf16 (N,K)
    const float* __restrict__ b3,            // [256]
    float* __restrict__ Out) {               // [16384,256] f32
    __shared__ __attribute__((aligned(16))) unsigned short lsA[TILE * BK];
    __shared__ __attribute__((aligned(16))) unsigned short lsB[TILE * BK];
    const int tid = threadIdx.x, lane = tid & 63, wave = tid >> 6;
    const int wm = (wave >> 1) * 64, wn = (wave & 1) * 64;
    const int a0 = blockIdx.y * TILE;
    const int n0 = blockIdx.x * TILE;

    f32x4 acc[4][4];
#pragma unroll
    for (int r = 0; r < 4; ++r)
#pragma unroll
        for (int c = 0; c < 4; ++c) acc[r][c] = (f32x4)0.0f;

    gemm_core<H2>(X2, W3b, lsA, lsB, a0, n0, lane, wave, wm, wn, acc);

    const int q = lane >> 4, m16 = lane & 15;
#pragma unroll
    for (int c = 0; c < 4; ++c) {
        const int gn = n0 + wn + c * 16 + m16;
        const float b3v = b3[gn];
#pragma unroll
        for (int r = 0; r < 4; ++r) {
#pragma unroll
            for (int i = 0; i < 4; ++i) {
                const int gm = a0 + wm + r * 16 + q * 4 + i;
                Out[gm * DOUT + gn] = acc[r][c][i] + b3v;
            }
        }
    }
}

extern "C" void kernel_launch(void* const* d_in, const int* in_sizes, int n_in,
                              void* d_out, int out_size, void* d_ws, size_t ws_size,
                              hipStream_t stream) {
    const float* x  = (const float*)d_in[0];
    const float* W1 = (const float*)d_in[1];
    const float* b1 = (const float*)d_in[2];
    const float* W2 = (const float*)d_in[3];
    const float* b2 = (const float*)d_in[4];
    const float* W3 = (const float*)d_in[5];
    const float* b3 = (const float*)d_in[6];
    float* out = (float*)d_out;

    char* ws = (char*)d_ws;
    unsigned short* x_bf  = (unsigned short*)ws;                         // 33,554,432 B
    unsigned short* w1_bf = (unsigned short*)(ws + 33554432);            //  8,388,608 B
    unsigned short* w3_bf = (unsigned short*)(ws + 33554432 + 8388608);  //    262,144 B
    unsigned short* x2_bf = (unsigned short*)(ws + 33554432 + 8388608 + 262144); // 16,777,216 B

    // one launch for all fp32->bf16 conversions
    cvt3_kernel<<<(NX4 + NW14 + NW34) / 256, 256, 0, stream>>>(
        x, W1, W3, x_bf, w1_bf, w3_bf);

    // GEMM1 + fused layer 2: grid = (32, 128)
    gemm1_fused<<<dim3(H1 / TILE, B_ROWS / TILE), 256, 0, stream>>>(
        x_bf, w1_bf, b1, W2, b2, x2_bf);

    // GEMM3: grid = (2, 128)
    gemm3_kernel<<<dim3(DOUT / TILE, B_ROWS / TILE), 256, 0, stream>>>(
        x2_bf, w3_bf, b3, out);
}

// Round 3
// 319.861 us; speedup vs baseline: 1.0703x; 1.0686x over previous
//
#include <hip/hip_runtime.h>
#include <cstdint>

// AdaptiveNet: x[16384,1024] -> fc1(4096)+sigmoid -> grouped(512 groups of 8)+sigmoid -> fc3(256)
// bf16 MFMA 16x16x32. R3: BK=64 (half the barriers per FLOP, 32 MFMA per barrier-pair),
// 8-slot LDS swizzle keeps fragment reads conflict-free and staging coalesced.

#define B_ROWS 16384
#define DIN 1024
#define H1  4096
#define H2  512
#define DOUT 256
#define TILE 128
#define BK 64

#define NX4  (B_ROWS * DIN / 4)   // 4194304
#define NW14 (H1 * DIN / 4)       // 1048576
#define NW34 (DOUT * H2 / 4)      // 32768

typedef __bf16 bf16x8 __attribute__((ext_vector_type(8)));
typedef float f32x4 __attribute__((ext_vector_type(4)));

__device__ __forceinline__ unsigned short f2bf(float f) {
    union { float f; uint32_t u; } v; v.f = f;
    uint32_t u = v.u;
    u += 0x7FFFu + ((u >> 16) & 1u);   // round-to-nearest-even
    return (unsigned short)(u >> 16);
}

__device__ __forceinline__ float sigmoidf_fast(float x) {
    return 1.0f / (1.0f + __expf(-x));
}

// one launch converts x, W1, W3 fp32->bf16 (all ranges multiples of 256 threads)
__global__ __launch_bounds__(256) void cvt3_kernel(
    const float* __restrict__ x, const float* __restrict__ w1,
    const float* __restrict__ w3, unsigned short* __restrict__ xo,
    unsigned short* __restrict__ w1o, unsigned short* __restrict__ w3o) {
    int i = blockIdx.x * 256 + threadIdx.x;
    const float* src; unsigned short* dst; int j;
    if (i < NX4)              { src = x;  dst = xo;  j = i; }
    else if (i < NX4 + NW14)  { src = w1; dst = w1o; j = i - NX4; }
    else                      { src = w3; dst = w3o; j = i - NX4 - NW14; }
    float4 v = ((const float4*)src)[j];
    ushort4 o;
    o.x = f2bf(v.x); o.y = f2bf(v.y); o.z = f2bf(v.z); o.w = f2bf(v.w);
    ((ushort4*)dst)[j] = o;
}

__device__ __forceinline__ void load_lds16(const void* g, void* l) {
    __builtin_amdgcn_global_load_lds(
        (const __attribute__((address_space(1))) void*)g,
        (__attribute__((address_space(3))) void*)l, 16, 0, 0);
}

// Core K-loop, BK=64: C[128,128] tile, A row-major [M,K], B stored as [N,K], bf16.
// LDS row = 128B = 8 chunks of 16B; row r's chunks rotated by (r&7) so that a
// ds_read_b128 of 16 rows at fixed k spreads over all 32 banks at 2 lanes/bank
// (free, m136). Swizzle realized by permuting each staging lane's global k-chunk;
// the 8 lanes of one row still cover the same 128B global segment (coalesced).
// Inner loop = 2 k-halves so fragment register count stays at 8 x bf16x8.
template <int K>
__device__ __forceinline__ void gemm_core(const unsigned short* __restrict__ A,
                                          const unsigned short* __restrict__ Bm,
                                          unsigned short* lsA, unsigned short* lsB,
                                          int a_row0, int b_row0,
                                          int lane, int wave, int wm, int wn,
                                          f32x4 acc[4][4]) {
    const int q = lane >> 4, m16 = lane & 15;

    // ---- staging addresses (loop-invariant): 4 chunks of 1KB per matrix per wave
    int gA[4], gB[4], lo[4];
#pragma unroll
    for (int i = 0; i < 4; ++i) {
        const int ch = wave * 4 + i;           // 0..15, chunk = 8 rows x 128B
        const int r  = ch * 8 + (lane >> 3);   // row this lane stages
        const int kc = ((lane & 7) - (lane >> 3)) & 7;  // swizzled k-chunk
        gA[i] = (a_row0 + r) * K + kc * 8;
        gB[i] = (b_row0 + r) * K + kc * 8;
        lo[i] = ch * 512;                      // elements (1KB); HW adds lane*16B
    }
    // ---- fragment-read offsets: slot s = (chunk + (row&7)) & 7, chunk = h*4+q
    int ra[2][4], rb[2][4];
#pragma unroll
    for (int h = 0; h < 2; ++h)
#pragma unroll
        for (int t = 0; t < 4; ++t) {
            const int s = ((h * 4 + q + (m16 & 7)) & 7) * 8;
            ra[h][t] = (wm + t * 16 + m16) * BK + s;
            rb[h][t] = (wn + t * 16 + m16) * BK + s;
        }

    for (int kt = 0; kt < K / BK; ++kt) {
        __syncthreads();                      // protect LDS from prior iter readers
        const int k0 = kt * BK;
#pragma unroll
        for (int i = 0; i < 4; ++i) {
            load_lds16(A + gA[i] + k0, lsA + lo[i]);
            load_lds16(Bm + gB[i] + k0, lsB + lo[i]);
        }
        __syncthreads();                      // staged (syncthreads drains vmcnt)
#pragma unroll
        for (int h = 0; h < 2; ++h) {
            bf16x8 af[4], bfr[4];
#pragma unroll
            for (int t = 0; t < 4; ++t) af[t]  = *(const bf16x8*)(lsA + ra[h][t]);
#pragma unroll
            for (int t = 0; t < 4; ++t) bfr[t] = *(const bf16x8*)(lsB + rb[h][t]);
#pragma unroll
            for (int r = 0; r < 4; ++r)
#pragma unroll
                for (int c = 0; c < 4; ++c)
                    acc[r][c] = __builtin_amdgcn_mfma_f32_16x16x32_bf16(
                        af[r], bfr[c], acc[r][c], 0, 0, 0);
        }
    }
}

// GEMM1: h = sigmoid(x @ W1^T + b1); fused layer2: x2 = sigmoid(groupdot(h,W2)+b2)
__global__ __launch_bounds__(256, 2) void gemm1_fused(
    const unsigned short* __restrict__ Xb,   // [16384,1024] bf16
    const unsigned short* __restrict__ W1b,  // [4096,1024]  bf16 (N,K)
    const float* __restrict__ b1,            // [4096]
    const float* __restrict__ W2,            // [512*8] flat; W2[g][s] = W2[gn]
    const float* __restrict__ b2,            // [512]
    unsigned short* __restrict__ X2) {       // [16384,512] bf16
    __shared__ __attribute__((aligned(16))) unsigned short lsA[TILE * BK];
    __shared__ __attribute__((aligned(16))) unsigned short lsB[TILE * BK];
    const int tid = threadIdx.x, lane = tid & 63, wave = tid >> 6;
    const int wm = (wave >> 1) * 64, wn = (wave & 1) * 64;
    const int a0 = blockIdx.y * TILE;
    const int n0 = blockIdx.x * TILE;

    f32x4 acc[4][4];
#pragma unroll
    for (int r = 0; r < 4; ++r)
#pragma unroll
        for (int c = 0; c < 4; ++c) acc[r][c] = (f32x4)0.0f;

    gemm_core<DIN>(Xb, W1b, lsA, lsB, a0, n0, lane, wave, wm, wn, acc);

    // Epilogue. C/D layout (m89): col = lane&15, row = (lane>>4)*4 + reg.
    const int q = lane >> 4, m16 = lane & 15;
#pragma unroll
    for (int c = 0; c < 4; ++c) {
        const int gn = n0 + wn + c * 16 + m16;        // h column
        const float w2v = W2[gn];                     // gn == g*8 + s
        const float b1v = b1[gn];
        const int g = gn >> 3;
        const float b2v = b2[g];
#pragma unroll
        for (int r = 0; r < 4; ++r) {
#pragma unroll
            for (int i = 0; i < 4; ++i) {
                const int gm = a0 + wm + r * 16 + q * 4 + i;
                float h = sigmoidf_fast(acc[r][c][i] + b1v);
                float v = h * w2v;
                // group of 8 consecutive columns == 8 adjacent lanes
                v += __shfl_xor(v, 1, 64);
                v += __shfl_xor(v, 2, 64);
                v += __shfl_xor(v, 4, 64);
                if ((lane & 7) == 0)
                    X2[gm * H2 + g] = f2bf(sigmoidf_fast(v + b2v));
            }
        }
    }
}

// GEMM3: out = x2 @ W3^T + b3, fp32 out [16384, 256]
__global__ __launch_bounds__(256, 2) void gemm3_kernel(
    const unsigned short* __restrict__ X2,   // [16384,512] bf16
    const unsigned short* __restrict__ W3b,  // [256,512] bf16 (N,K)
    const float* __restrict__ b3,            // [256]
    float* __restrict__ Out) {               // [16384,256] f32
    __shared__ __attribute__((aligned(16))) unsigned short lsA[TILE * BK];
    __shared__ __attribute__((aligned(16))) unsigned short lsB[TILE * BK];
    const int tid = threadIdx.x, lane = tid & 63, wave = tid >> 6;
    const int wm = (wave >> 1) * 64, wn = (wave & 1) * 64;
    const int a0 = blockIdx.y * TILE;
    const int n0 = blockIdx.x * TILE;

    f32x4 acc[4][4];
#pragma unroll
    for (int r = 0; r < 4; ++r)
#pragma unroll
        for (int c = 0; c < 4; ++c) acc[r][c] = (f32x4)0.0f;

    gemm_core<H2>(X2, W3b, lsA, lsB, a0, n0, lane, wave, wm, wn, acc);

    const int q = lane >> 4, m16 = lane & 15;
#pragma unroll
    for (int c = 0; c < 4; ++c) {
        const int gn = n0 + wn + c * 16 + m16;
        const float b3v = b3[gn];
#pragma unroll
        for (int r = 0; r < 4; ++r) {
#pragma unroll
            for (int i = 0; i < 4; ++i) {
                const int gm = a0 + wm + r * 16 + q * 4 + i;
                Out[gm * DOUT + gn] = acc[r][c][i] + b3v;
            }
        }
    }
}

extern "C" void kernel_launch(void* const* d_in, const int* in_sizes, int n_in,
                              void* d_out, int out_size, void* d_ws, size_t ws_size,
                              hipStream_t stream) {
    const float* x  = (const float*)d_in[0];
    const float* W1 = (const float*)d_in[1];
    const float* b1 = (const float*)d_in[2];
    const float* W2 = (const float*)d_in[3];
    const float* b2 = (const float*)d_in[4];
    const float* W3 = (const float*)d_in[5];
    const float* b3 = (const float*)d_in[6];
    float* out = (float*)d_out;

    char* ws = (char*)d_ws;
    unsigned short* x_bf  = (unsigned short*)ws;                         // 33,554,432 B
    unsigned short* w1_bf = (unsigned short*)(ws + 33554432);            //  8,388,608 B
    unsigned short* w3_bf = (unsigned short*)(ws + 33554432 + 8388608);  //    262,144 B
    unsigned short* x2_bf = (unsigned short*)(ws + 33554432 + 8388608 + 262144); // 16,777,216 B

    // one launch for all fp32->bf16 conversions
    cvt3_kernel<<<(NX4 + NW14 + NW34) / 256, 256, 0, stream>>>(
        x, W1, W3, x_bf, w1_bf, w3_bf);

    // GEMM1 + fused layer 2: grid = (32, 128)
    gemm1_fused<<<dim3(H1 / TILE, B_ROWS / TILE), 256, 0, stream>>>(
        x_bf, w1_bf, b1, W2, b2, x2_bf);

    // GEMM3: grid = (2, 128)
    gemm3_kernel<<<dim3(DOUT / TILE, B_ROWS / TILE), 256, 0, stream>>>(
        x2_bf, w3_bf, b3, out);
}